// Round 12
// baseline (123.877 us; speedup 1.0000x reference)
//
#include <hip/hip_runtime.h>
#include <cstdint>
#include <cstddef>

typedef unsigned short u16;
typedef unsigned int u32;
typedef __attribute__((ext_vector_type(8))) __bf16 bf16x8;
typedef __attribute__((ext_vector_type(8))) u16 u16x8;
typedef __attribute__((ext_vector_type(4))) float f32x4;

#define N_SEQ   2048
#define HDIM    32
// (hd^-0.5) * log2(e): Q pre-scaled so attn uses bare exp2
#define QSCALE_LOG2E 0.2550540261150831f

#if __has_builtin(__builtin_amdgcn_exp2f)
#define EXP2(x) __builtin_amdgcn_exp2f(x)
#else
#define EXP2(x) exp2f(x)
#endif

__device__ __forceinline__ u16 f2bf(float f){
  union { float f; u32 i; } v; v.f = f;
  return (u16)((v.i + 0x7FFFu + ((v.i >> 16) & 1u)) >> 16);
}
__device__ __forceinline__ u32 fbits(float f){
  union { float f; u32 i; } v; v.f = f; return v.i;
}
__device__ __forceinline__ u32 pk2bf(float a, float b){
  return ((fbits(a) + 0x8000u) >> 16) | ((fbits(b) + 0x8000u) & 0xFFFF0000u);
}
__device__ __forceinline__ f32x4 mfma_bf16(bf16x8 a, bf16x8 b, f32x4 c){
  return __builtin_amdgcn_mfma_f32_16x16x32_bf16(a, b, c, 0, 0, 0);
}
union U8 { u16x8 u; bf16x8 b; };
union U2 { u32 w[2]; uint64_t q; };

// ---------------------------------------------------------------------------
// Kernel 1: W [256][768] fp32 -> Wtp, PACKED fragment-linear bf16:
// Wtp[((c>>4)*8 + (k>>5))*512 + (c&15)*32 + ((k>>3)&3)*8 + (k&7)]
// so a qkv B-fragment load is 1KB contiguous (8 CLs, fully coalesced).
// ---------------------------------------------------------------------------
__global__ __launch_bounds__(256) void wt_kernel(const float* __restrict__ W,
                                                 u16* __restrict__ Wtp){
  int t  = threadIdx.x;
  int tx = t & 31, ty = t >> 5;
  int n0 = blockIdx.x * 32;
  int k0 = blockIdx.y * 32;
#pragma unroll
  for (int i = 0; i < 4; ++i){
    int k = k0 + ty + i*8;
    int c = n0 + tx;
    u16 v = f2bf(W[k*768 + c]);
    Wtp[((c>>4)*8 + (k>>5))*512 + (c&15)*32 + ((k>>3)&3)*8 + (k&7)] = v;
  }
}

// ---------------------------------------------------------------------------
// Kernel 2: QKV = x @ W + b.  1D grid 768, XCD-swizzled.  Each block: one
// 64-row m-tile x 128 output cols (2 n-subtiles, type-uniform q|q|k|k|v|v).
// x staged ONCE to LDS + A-frags held in regs across both subtiles -> x CL
// traffic halved vs 64-col blocks.  B-frags 1KB contiguous from packed Wtp.
// Epilogue LDS-staged coalesced stores; V tiled Vt[bh][kb][d32][kk32].
// ---------------------------------------------------------------------------
__global__ __launch_bounds__(256) void qkv_kernel(const float* __restrict__ X,
                                                  const u16* __restrict__ Wtp,
                                                  const float* __restrict__ bias,
                                                  u16* __restrict__ Q,
                                                  u16* __restrict__ K,
                                                  u16* __restrict__ Vt){
  __shared__ __align__(16) u16 SM[64*264];  // 33.8 KB: x-stage, then epilogue
  int bid = blockIdx.x;
  int xcd = bid & 7;
  int idx = bid >> 3;                     // 0..95
  int mt  = 8*(idx & 15) + xcd;           // m-tile 0..127
  int nb  = idx >> 4;                     // 0..5
  int tid = threadIdx.x;
  int wave = tid >> 6, lane = tid & 63;
  int l16 = lane & 15, quad = lane >> 4;
  int m0 = mt * 64;
  int n0 = nb * 128;                      // 128 output cols (type-uniform)
  const int three = n0 >> 8;              // 0=q 1=k 2=v (block-uniform)

  // ---- stage x tile [64][256] fp32 -> bf16 LDS, coalesced ----
  const float* Xblk = X + m0 * 256;
#pragma unroll
  for (int i = 0; i < 16; ++i){
    int e = i*1024 + tid*4;               // 4KB contiguous per i
    f32x4 v = *(const f32x4*)(Xblk + e);
    int row = e >> 8, col = e & 255;
    U2 pk; pk.w[0] = pk2bf(v[0], v[1]); pk.w[1] = pk2bf(v[2], v[3]);
    *(uint64_t*)(&SM[row*264 + col]) = pk.q;
  }
  __syncthreads();

  // ---- A-frags from LDS, held in regs for BOTH n-subtiles ----
  int mrow = wave*16 + l16;
  U8 af[8];
#pragma unroll
  for (int k = 0; k < 8; ++k)
    af[k].u = *(const u16x8*)(&SM[mrow*264 + k*32 + quad*8]);
  __syncthreads();                        // SM reused by epilogue below

  int b_ = m0 >> 11, nseq0 = m0 & 2047;
  float scl = (three == 0) ? QSCALE_LOG2E : 1.0f;

  for (int jt = 0; jt < 2; ++jt){
    int nn = n0 + jt*64;

    // ---- MFMA over K=256; B-frags 1KB contiguous from packed Wtp ----
    f32x4 acc[4] = {};
#pragma unroll
    for (int k = 0; k < 8; ++k)
#pragma unroll
      for (int s = 0; s < 4; ++s){
        U8 b;
        b.u = *(const u16x8*)(Wtp + (((nn>>4) + s)*8 + k)*512 + l16*32 + quad*8);
        acc[s] = mfma_bf16(af[k].b, b.b, acc[s]);
      }

    // ---- epilogue for this subtile ----
    if (three == 2){
      // V: stage [col][tok]
#pragma unroll
      for (int s = 0; s < 4; ++s){
        int cl = s*16 + l16;
        float bv = bias[nn + cl];
        int tok = wave*16 + quad*4;
        U2 pk;
        pk.w[0] = pk2bf(acc[s][0] + bv, acc[s][1] + bv);
        pk.w[1] = pk2bf(acc[s][2] + bv, acc[s][3] + bv);
        *(uint64_t*)(&SM[cl*68 + tok]) = pk.q;
      }
      __syncthreads();
#pragma unroll
      for (int i = 0; i < 16; ++i){
        int cl = wave*16 + i;
        int c = nn + cl;
        int h = (c >> 5) & 7, d = c & 31;
        int bh = b_*8 + h;
        int kb = (nseq0 >> 5) + (lane >> 5);
        int kk = lane & 31;
        Vt[((bh*64 + kb)*32 + d)*32 + kk] = SM[cl*68 + lane];
      }
    } else {
      // Q/K: stage token-major [tok][col]
#pragma unroll
      for (int s = 0; s < 4; ++s){
        int cl = s*16 + l16;
        float bv = bias[nn + cl];
#pragma unroll
        for (int r = 0; r < 4; ++r)
          SM[(wave*16 + quad*4 + r)*68 + cl] = f2bf((acc[s][r] + bv) * scl);
      }
      __syncthreads();
      u16* dst = (three == 0) ? Q : K;
#pragma unroll
      for (int j = 0; j < 2; ++j){
        int unit = tid + j*256;             // 512 units: tok x ph x chunk
        int tok = unit & 63;
        int rest = unit >> 6;               // 0..7
        int ph = rest >> 2, chunk = rest & 3;
        int h = ((nn >> 5) + ph) & 7;
        int bh = b_*8 + h;
        u16x8 v = *(const u16x8*)(&SM[tok*68 + ph*32 + chunk*8]);
        *(u16x8*)(&dst[(bh*N_SEQ + nseq0 + tok)*HDIM + chunk*8]) = v;
      }
    }
    __syncthreads();   // SM reuse by next subtile
  }
}

// ---------------------------------------------------------------------------
// Kernel 3: attention.  Block = 64 q-rows of one bh (4 qg of 16), 4 waves
// k-split (stride 4).  K AND V frags loaded ONCE per tile (8 VMEM insts, 64
// CLs) and held in regs across both qg-pairs -> per-64q CL traffic 64 (R11:
// 96).  Grid 1024 XCD-swizzled -> all blocks co-resident (4/CU).  P double-
// buffer per wave (2 sub-slots); Obuf aliases P region.
// ---------------------------------------------------------------------------
__global__ __launch_bounds__(256, 4) void attn_kernel(const u16* __restrict__ Q,
                                                      const u16* __restrict__ Kg,
                                                      const u16* __restrict__ Vt,
                                                      float* __restrict__ out){
  __shared__ __align__(16) u16 smem[4*2*16*72];   // 18432 B (P | Obuf alias)
  __shared__ float Lbuf[4][32];
  u16  (*Ps)[2][16][72] = (u16 (*)[2][16][72])smem;
  float (*Obuf)[32][36] = (float (*)[32][36])smem;

  int bid = blockIdx.x;
  int bh = (bid & 7)*4 + ((bid >> 3) & 3);
  int g  = bid >> 5;                      // 0..31: 64-row q-group
  int r0 = g * 64;
  int tid = threadIdx.x, wave = tid >> 6, lane = tid & 63;
  int l16 = lane & 15, quad = lane >> 4;

  const u16* Qb = Q  + bh * (N_SEQ*HDIM);
  const u16* Kb = Kg + bh * (N_SEQ*HDIM);
  const u16* Vb = Vt + bh * (64*32*32);   // tiled [kb][d][kk]

  const int  T       = (r0 < 1024) ? 16 : (g + 1);
  const bool hasMask = (r0 >= 1024);

  U8 qt[4];
#pragma unroll
  for (int qg = 0; qg < 4; ++qg)
    qt[qg].u = *(const u16x8*)(Qb + (r0 + qg*16 + l16)*HDIM + quad*8);

  U8 onesu;
#pragma unroll
  for (int j = 0; j < 8; ++j) onesu.u[j] = 0x3F80;   // bf16 1.0
  bf16x8 ones = onesu.b;

  f32x4 O[4][2] = {};
  f32x4 L[4] = {};

  for (int t = wave; t < T; t += 4){
    int k0 = t * 64;
    // K + V fragments loaded once per tile, held across both qg-pairs
    U8 kf[4];
#pragma unroll
    for (int s = 0; s < 4; ++s)
      kf[s].u = *(const u16x8*)(Kb + (k0 + s*16 + l16)*HDIM + quad*8);
    U8 vf[2][2];
#pragma unroll
    for (int kc = 0; kc < 2; ++kc)
#pragma unroll
      for (int nd = 0; nd < 2; ++nd)
        vf[kc][nd].u = *(const u16x8*)(Vb + (size_t)(t*2 + kc)*1024 + (nd*16 + l16)*32 + quad*8);

    bool mask = hasMask && (t == T - 1);

#pragma unroll
    for (int pr = 0; pr < 2; ++pr){
      // ---- QK + exp for qg = 2pr, 2pr+1 ----
#pragma unroll
      for (int sub = 0; sub < 2; ++sub){
        int qg = pr*2 + sub;
        f32x4 ST[4];
#pragma unroll
        for (int s = 0; s < 4; ++s){
          f32x4 z = {};
          ST[s] = mfma_bf16(kf[s].b, qt[qg].b, z);
        }
        u16 (*P)[72] = Ps[wave][sub];
        if (mask){
          int iq = r0 + qg*16 + l16;
#pragma unroll
          for (int s = 0; s < 4; ++s){
            int jb = k0 + s*16 + quad*4;
            float p0 = (jb+0 > iq) ? 0.0f : EXP2(ST[s][0]);
            float p1 = (jb+1 > iq) ? 0.0f : EXP2(ST[s][1]);
            float p2 = (jb+2 > iq) ? 0.0f : EXP2(ST[s][2]);
            float p3 = (jb+3 > iq) ? 0.0f : EXP2(ST[s][3]);
            U2 pk; pk.w[0] = pk2bf(p0, p1); pk.w[1] = pk2bf(p2, p3);
            *(uint64_t*)(&P[l16][s*16 + quad*4]) = pk.q;
          }
        } else {
#pragma unroll
          for (int s = 0; s < 4; ++s){
            U2 pk;
            pk.w[0] = pk2bf(EXP2(ST[s][0]), EXP2(ST[s][1]));
            pk.w[1] = pk2bf(EXP2(ST[s][2]), EXP2(ST[s][3]));
            *(uint64_t*)(&P[l16][s*16 + quad*4]) = pk.q;
          }
        }
      }

      // ---- PV for both qg of this pair (V already in regs) ----
#pragma unroll
      for (int sub = 0; sub < 2; ++sub){
        int qg = pr*2 + sub;
        u16 (*P)[72] = Ps[wave][sub];
#pragma unroll
        for (int kc = 0; kc < 2; ++kc){
          U8 pf; pf.u = *(const u16x8*)(&P[l16][kc*32 + quad*8]);
          O[qg][0] = mfma_bf16(pf.b, vf[kc][0].b, O[qg][0]);
          O[qg][1] = mfma_bf16(pf.b, vf[kc][1].b, O[qg][1]);
          L[qg]    = mfma_bf16(pf.b, ones, L[qg]);
        }
      }
    }
  }

  __syncthreads();   // all PV done -> safe to alias P region as Obuf

  int b_ = bh >> 3, h = bh & 7;
#pragma unroll
  for (int pass = 0; pass < 2; ++pass){
    if (pass) __syncthreads();
#pragma unroll
    for (int sub = 0; sub < 2; ++sub){
      int qg = pass*2 + sub;
#pragma unroll
      for (int r = 0; r < 4; ++r){
        int row = sub*16 + quad*4 + r;
        Obuf[wave][row][l16]      = O[qg][0][r];
        Obuf[wave][row][16 + l16] = O[qg][1][r];
      }
      if (l16 == 0){
#pragma unroll
        for (int r = 0; r < 4; ++r)
          Lbuf[wave][sub*16 + quad*4 + r] = L[qg][r];
      }
    }
    __syncthreads();
    {
      int row = tid >> 3;               // 0..31
      int c4  = (tid & 7) * 4;          // 0..28
      f32x4 a = *(const f32x4*)(&Obuf[0][row][c4]);
      float Ls = Lbuf[0][row];
#pragma unroll
      for (int w = 1; w < 4; ++w){
        f32x4 b = *(const f32x4*)(&Obuf[w][row][c4]);
        a[0] += b[0]; a[1] += b[1]; a[2] += b[2]; a[3] += b[3];
        Ls += Lbuf[w][row];
      }
      float inv = 1.0f / Ls;
      a[0] *= inv; a[1] *= inv; a[2] *= inv; a[3] *= inv;
      *(f32x4*)(&out[(b_*N_SEQ + r0 + pass*32 + row)*256 + h*32 + c4]) = a;
    }
  }
}

// ---------------------------------------------------------------------------
extern "C" void kernel_launch(void* const* d_in, const int* in_sizes, int n_in,
                              void* d_out, int out_size, void* d_ws, size_t ws_size,
                              hipStream_t stream) {
  const float* x    = (const float*)d_in[0];   // [4,2048,256] fp32
  const float* W    = (const float*)d_in[1];   // [256,768]    fp32
  const float* bias = (const float*)d_in[2];   // [768]        fp32
  float* out = (float*)d_out;                  // [4,2048,256] fp32

  char* ws = (char*)d_ws;
  u16* Wtp   = (u16*)(ws);                     // 393,216 B packed
  u16* Kbuf  = (u16*)(ws + 393216);            // 4 MB
  u16* Vtbuf = (u16*)(ws + 393216 + 4194304);  // 4 MB (tiled [bh][kb][d][kk])
  u16* Qbuf  = (u16*)(ws + 393216 + 2*4194304);// 4 MB

  wt_kernel  <<<dim3(24, 8), 256, 0, stream>>>(W, Wtp);
  qkv_kernel <<<dim3(768),   256, 0, stream>>>(x, Wtp, bias, Qbuf, Kbuf, Vtbuf);
  attn_kernel<<<dim3(1024),  256, 0, stream>>>(Qbuf, Kbuf, Vtbuf, out);
}

// Round 13
// 107.206 us; speedup vs baseline: 1.1555x; 1.1555x over previous
//
#include <hip/hip_runtime.h>
#include <cstdint>
#include <cstddef>

typedef unsigned short u16;
typedef unsigned int u32;
typedef __attribute__((ext_vector_type(8))) __bf16 bf16x8;
typedef __attribute__((ext_vector_type(8))) u16 u16x8;
typedef __attribute__((ext_vector_type(4))) float f32x4;

#define N_SEQ   2048
#define HDIM    32
// (hd^-0.5) * log2(e): Q pre-scaled so attn uses bare exp2
#define QSCALE_LOG2E 0.2550540261150831f

#if __has_builtin(__builtin_amdgcn_exp2f)
#define EXP2(x) __builtin_amdgcn_exp2f(x)
#else
#define EXP2(x) exp2f(x)
#endif

__device__ __forceinline__ u16 f2bf(float f){
  union { float f; u32 i; } v; v.f = f;
  return (u16)((v.i + 0x7FFFu + ((v.i >> 16) & 1u)) >> 16);
}
__device__ __forceinline__ u32 fbits(float f){
  union { float f; u32 i; } v; v.f = f; return v.i;
}
__device__ __forceinline__ u32 pk2bf(float a, float b){
  return ((fbits(a) + 0x8000u) >> 16) | ((fbits(b) + 0x8000u) & 0xFFFF0000u);
}
__device__ __forceinline__ f32x4 mfma_bf16(bf16x8 a, bf16x8 b, f32x4 c){
  return __builtin_amdgcn_mfma_f32_16x16x32_bf16(a, b, c, 0, 0, 0);
}
union U8 { u16x8 u; bf16x8 b; };
union U2 { u32 w[2]; uint64_t q; };
union U4 { u32 w[4]; u16x8 u; bf16x8 b; };

// ---------------------------------------------------------------------------
// Kernel 1: W [256][768] fp32 -> Wtp, PACKED fragment-linear bf16:
// Wtp[((c>>4)*8 + (k>>5))*512 + (c&15)*32 + ((k>>3)&3)*8 + (k&7)]
// so a qkv B-fragment load is 1KB contiguous (8 CLs, fully coalesced).
// ---------------------------------------------------------------------------
__global__ __launch_bounds__(256) void wt_kernel(const float* __restrict__ W,
                                                 u16* __restrict__ Wtp){
  int t  = threadIdx.x;
  int tx = t & 31, ty = t >> 5;
  int n0 = blockIdx.x * 32;
  int k0 = blockIdx.y * 32;
#pragma unroll
  for (int i = 0; i < 4; ++i){
    int k = k0 + ty + i*8;
    int c = n0 + tx;
    u16 v = f2bf(W[k*768 + c]);
    Wtp[((c>>4)*8 + (k>>5))*512 + (c&15)*32 + ((k>>3)&3)*8 + (k&7)] = v;
  }
}

// ---------------------------------------------------------------------------
// Kernel 2: QKV = x @ W + b.  1D grid 768, XCD-swizzled.  Each block: one
// 64-row m-tile x 128 output cols (2 n-subtiles, type-uniform q|q|k|k|v|v).
// x staged ONCE to LDS + A-frags held in regs across both subtiles.
// B-frags 1KB contiguous from packed Wtp.  LDS-staged coalesced stores;
// V tiled Vt[bh][kb][d32][kk32].
// ---------------------------------------------------------------------------
__global__ __launch_bounds__(256) void qkv_kernel(const float* __restrict__ X,
                                                  const u16* __restrict__ Wtp,
                                                  const float* __restrict__ bias,
                                                  u16* __restrict__ Q,
                                                  u16* __restrict__ K,
                                                  u16* __restrict__ Vt){
  __shared__ __align__(16) u16 SM[64*264];  // 33.8 KB: x-stage, then epilogue
  int bid = blockIdx.x;
  int xcd = bid & 7;
  int idx = bid >> 3;                     // 0..95
  int mt  = 8*(idx & 15) + xcd;           // m-tile 0..127
  int nb  = idx >> 4;                     // 0..5
  int tid = threadIdx.x;
  int wave = tid >> 6, lane = tid & 63;
  int l16 = lane & 15, quad = lane >> 4;
  int m0 = mt * 64;
  int n0 = nb * 128;                      // 128 output cols (type-uniform)
  const int three = n0 >> 8;              // 0=q 1=k 2=v (block-uniform)

  // ---- stage x tile [64][256] fp32 -> bf16 LDS, coalesced ----
  const float* Xblk = X + m0 * 256;
#pragma unroll
  for (int i = 0; i < 16; ++i){
    int e = i*1024 + tid*4;               // 4KB contiguous per i
    f32x4 v = *(const f32x4*)(Xblk + e);
    int row = e >> 8, col = e & 255;
    U2 pk; pk.w[0] = pk2bf(v[0], v[1]); pk.w[1] = pk2bf(v[2], v[3]);
    *(uint64_t*)(&SM[row*264 + col]) = pk.q;
  }
  __syncthreads();

  // ---- A-frags from LDS, held in regs for BOTH n-subtiles ----
  int mrow = wave*16 + l16;
  U8 af[8];
#pragma unroll
  for (int k = 0; k < 8; ++k)
    af[k].u = *(const u16x8*)(&SM[mrow*264 + k*32 + quad*8]);
  __syncthreads();                        // SM reused by epilogue below

  int b_ = m0 >> 11, nseq0 = m0 & 2047;
  float scl = (three == 0) ? QSCALE_LOG2E : 1.0f;

  for (int jt = 0; jt < 2; ++jt){
    int nn = n0 + jt*64;

    // ---- MFMA over K=256; B-frags 1KB contiguous from packed Wtp ----
    f32x4 acc[4] = {};
#pragma unroll
    for (int k = 0; k < 8; ++k)
#pragma unroll
      for (int s = 0; s < 4; ++s){
        U8 b;
        b.u = *(const u16x8*)(Wtp + (((nn>>4) + s)*8 + k)*512 + l16*32 + quad*8);
        acc[s] = mfma_bf16(af[k].b, b.b, acc[s]);
      }

    // ---- epilogue for this subtile ----
    if (three == 2){
      // V: stage [col][tok]
#pragma unroll
      for (int s = 0; s < 4; ++s){
        int cl = s*16 + l16;
        float bv = bias[nn + cl];
        int tok = wave*16 + quad*4;
        U2 pk;
        pk.w[0] = pk2bf(acc[s][0] + bv, acc[s][1] + bv);
        pk.w[1] = pk2bf(acc[s][2] + bv, acc[s][3] + bv);
        *(uint64_t*)(&SM[cl*68 + tok]) = pk.q;
      }
      __syncthreads();
#pragma unroll
      for (int i = 0; i < 16; ++i){
        int cl = wave*16 + i;
        int c = nn + cl;
        int h = (c >> 5) & 7, d = c & 31;
        int bh = b_*8 + h;
        int kb = (nseq0 >> 5) + (lane >> 5);
        int kk = lane & 31;
        Vt[((bh*64 + kb)*32 + d)*32 + kk] = SM[cl*68 + lane];
      }
    } else {
      // Q/K: stage token-major [tok][col]
#pragma unroll
      for (int s = 0; s < 4; ++s){
        int cl = s*16 + l16;
        float bv = bias[nn + cl];
#pragma unroll
        for (int r = 0; r < 4; ++r)
          SM[(wave*16 + quad*4 + r)*68 + cl] = f2bf((acc[s][r] + bv) * scl);
      }
      __syncthreads();
      u16* dst = (three == 0) ? Q : K;
#pragma unroll
      for (int j = 0; j < 2; ++j){
        int unit = tid + j*256;             // 512 units: tok x ph x chunk
        int tok = unit & 63;
        int rest = unit >> 6;               // 0..7
        int ph = rest >> 2, chunk = rest & 3;
        int h = ((nn >> 5) + ph) & 7;
        int bh = b_*8 + h;
        u16x8 v = *(const u16x8*)(&SM[tok*68 + ph*32 + chunk*8]);
        *(u16x8*)(&dst[(bh*N_SEQ + nseq0 + tok)*HDIM + chunk*8]) = v;
      }
    }
    __syncthreads();   // SM reuse by next subtile
  }
}

// ---------------------------------------------------------------------------
// Kernel 3: attention, NO P LDS round-trip.  The C-layout -> A-layout
// transform of P is a fixed quad-level lane permutation done in-register via
// ds_bpermute (same l16; quad' = 2*(quad&1)+{0,1}; source reg s=2kc+(quad>>1)).
// Block = 32 q-rows (2 qg) of one bh; 4 waves k-split (stride 4); grid 2048
// XCD-swizzled (bh per XCD group -> K/V L2-resident).  LDS only for the
// final O/L cross-wave combine.  p = exp2(S) (Q pre-scaled by log2e).
// ---------------------------------------------------------------------------
__global__ __launch_bounds__(256, 4) void attn_kernel(const u16* __restrict__ Q,
                                                      const u16* __restrict__ Kg,
                                                      const u16* __restrict__ Vt,
                                                      float* __restrict__ out){
  __shared__ __align__(8) float Obuf[4][32][36];  // 18.4 KB
  __shared__ float Lbuf[4][32];

  int bid = blockIdx.x;
  int bh = (bid & 7)*4 + ((bid >> 3) & 3);
  int g  = bid >> 5;                      // 0..63: 32-row q-group
  int r0 = g * 32;
  int tid = threadIdx.x, wave = tid >> 6, lane = tid & 63;
  int l16 = lane & 15, quad = lane >> 4;

  const u16* Qb = Q  + bh * (N_SEQ*HDIM);
  const u16* Kb = Kg + bh * (N_SEQ*HDIM);
  const u16* Vb = Vt + bh * (64*32*32);   // tiled [kb][d][kk]

  const int  T       = (r0 < 1024) ? 16 : (g >> 1) + 1;
  const bool hasMask = (r0 >= 1024);

  U8 qt[2];
  qt[0].u = *(const u16x8*)(Qb + (r0      + l16)*HDIM + quad*8);
  qt[1].u = *(const u16x8*)(Qb + (r0 + 16 + l16)*HDIM + quad*8);

  U8 onesu;
#pragma unroll
  for (int j = 0; j < 8; ++j) onesu.u[j] = 0x3F80;   // bf16 1.0
  bf16x8 ones = onesu.b;

  f32x4 O[2][2] = {};
  f32x4 L[2] = {};

  // bpermute lane addresses (bytes): source lane = quad'*16 + l16
  const int la0 = (((quad & 1) * 2) * 16 + l16) * 4;
  const int la1 = la0 + 64;
  const bool hiS = (quad >> 1);           // selects s = 2kc+1 source regs

  for (int t = wave; t < T; t += 4){
    int k0 = t * 64;
    U8 kf[4];
#pragma unroll
    for (int s = 0; s < 4; ++s)
      kf[s].u = *(const u16x8*)(Kb + (k0 + s*16 + l16)*HDIM + quad*8);
    U8 vf[2][2];
#pragma unroll
    for (int kc = 0; kc < 2; ++kc)
#pragma unroll
      for (int nd = 0; nd < 2; ++nd)
        vf[kc][nd].u = *(const u16x8*)(Vb + (size_t)(t*2 + kc)*1024 + (nd*16 + l16)*32 + quad*8);

    bool mask = hasMask && (t == T - 1);

#pragma unroll
    for (int qg = 0; qg < 2; ++qg){
      // ---- S^T = K Q^T : ST[s][r] = score(key k0+s*16+quad*4+r, q r0+qg*16+l16)
      f32x4 ST[4];
#pragma unroll
      for (int s = 0; s < 4; ++s){
        f32x4 z = {};
        ST[s] = mfma_bf16(kf[s].b, qt[qg].b, z);
      }

      // ---- p = exp2(s), mask, pack: pw[s][w] = keys s*16+quad*4+(2w,2w+1)
      u32 pw[4][2];
      if (mask){
        int iq = r0 + qg*16 + l16;
#pragma unroll
        for (int s = 0; s < 4; ++s){
          int jb = k0 + s*16 + quad*4;
          float p0 = (jb+0 > iq) ? 0.0f : EXP2(ST[s][0]);
          float p1 = (jb+1 > iq) ? 0.0f : EXP2(ST[s][1]);
          float p2 = (jb+2 > iq) ? 0.0f : EXP2(ST[s][2]);
          float p3 = (jb+3 > iq) ? 0.0f : EXP2(ST[s][3]);
          pw[s][0] = pk2bf(p0, p1); pw[s][1] = pk2bf(p2, p3);
        }
      } else {
#pragma unroll
        for (int s = 0; s < 4; ++s){
          pw[s][0] = pk2bf(EXP2(ST[s][0]), EXP2(ST[s][1]));
          pw[s][1] = pk2bf(EXP2(ST[s][2]), EXP2(ST[s][3]));
        }
      }

      // ---- in-register C->A transform via ds_bpermute, then PV ----
#pragma unroll
      for (int kc = 0; kc < 2; ++kc){
        int s0 = 2*kc, s1 = 2*kc + 1;
        u32 a00 = __builtin_amdgcn_ds_bpermute(la0, (int)pw[s0][0]);
        u32 a01 = __builtin_amdgcn_ds_bpermute(la0, (int)pw[s1][0]);
        u32 a10 = __builtin_amdgcn_ds_bpermute(la0, (int)pw[s0][1]);
        u32 a11 = __builtin_amdgcn_ds_bpermute(la0, (int)pw[s1][1]);
        u32 a20 = __builtin_amdgcn_ds_bpermute(la1, (int)pw[s0][0]);
        u32 a21 = __builtin_amdgcn_ds_bpermute(la1, (int)pw[s1][0]);
        u32 a30 = __builtin_amdgcn_ds_bpermute(la1, (int)pw[s0][1]);
        u32 a31 = __builtin_amdgcn_ds_bpermute(la1, (int)pw[s1][1]);
        U4 A;
        A.w[0] = hiS ? a01 : a00;
        A.w[1] = hiS ? a11 : a10;
        A.w[2] = hiS ? a21 : a20;
        A.w[3] = hiS ? a31 : a30;
        O[qg][0] = mfma_bf16(A.b, vf[kc][0].b, O[qg][0]);
        O[qg][1] = mfma_bf16(A.b, vf[kc][1].b, O[qg][1]);
        L[qg]    = mfma_bf16(A.b, ones, L[qg]);
      }
    }
  }

  // ---- cross-wave combine of the 4 key-splits ----
#pragma unroll
  for (int qg = 0; qg < 2; ++qg)
#pragma unroll
    for (int r = 0; r < 4; ++r){
      int row = qg*16 + quad*4 + r;
      Obuf[wave][row][l16]      = O[qg][0][r];
      Obuf[wave][row][16 + l16] = O[qg][1][r];
    }
  if (l16 == 0){
#pragma unroll
    for (int qg = 0; qg < 2; ++qg)
#pragma unroll
      for (int r = 0; r < 4; ++r)
        Lbuf[wave][qg*16 + quad*4 + r] = L[qg][r];
  }
  __syncthreads();

  {
    int row = tid >> 3;               // 0..31
    int c4  = (tid & 7) * 4;          // 0..28
    f32x4 a = *(const f32x4*)(&Obuf[0][row][c4]);
    float Ls = Lbuf[0][row];
#pragma unroll
    for (int w = 1; w < 4; ++w){
      f32x4 b = *(const f32x4*)(&Obuf[w][row][c4]);
      a[0] += b[0]; a[1] += b[1]; a[2] += b[2]; a[3] += b[3];
      Ls += Lbuf[w][row];
    }
    float inv = 1.0f / Ls;
    a[0] *= inv; a[1] *= inv; a[2] *= inv; a[3] *= inv;
    int b_ = bh >> 3, h = bh & 7;
    *(f32x4*)(&out[(b_*N_SEQ + r0 + row)*256 + h*32 + c4]) = a;
  }
}

// ---------------------------------------------------------------------------
extern "C" void kernel_launch(void* const* d_in, const int* in_sizes, int n_in,
                              void* d_out, int out_size, void* d_ws, size_t ws_size,
                              hipStream_t stream) {
  const float* x    = (const float*)d_in[0];   // [4,2048,256] fp32
  const float* W    = (const float*)d_in[1];   // [256,768]    fp32
  const float* bias = (const float*)d_in[2];   // [768]        fp32
  float* out = (float*)d_out;                  // [4,2048,256] fp32

  char* ws = (char*)d_ws;
  u16* Wtp   = (u16*)(ws);                     // 393,216 B packed
  u16* Kbuf  = (u16*)(ws + 393216);            // 4 MB
  u16* Vtbuf = (u16*)(ws + 393216 + 4194304);  // 4 MB (tiled [bh][kb][d][kk])
  u16* Qbuf  = (u16*)(ws + 393216 + 2*4194304);// 4 MB

  wt_kernel  <<<dim3(24, 8), 256, 0, stream>>>(W, Wtp);
  qkv_kernel <<<dim3(768),   256, 0, stream>>>(x, Wtp, bias, Qbuf, Kbuf, Vtbuf);
  attn_kernel<<<dim3(2048),  256, 0, stream>>>(Qbuf, Kbuf, Vtbuf, out);
}